// Round 1
// baseline (2133.674 us; speedup 1.0000x reference)
//
#include <hip/hip_runtime.h>
#include <math.h>

// Problem constants (setup_inputs is fixed): B=4, C=256, H=W=64, G=4, Cg=64, P=9.
// Layout choice: x [B, HW, C] row-major IS NHWC already -> all convs and the
// deformable gather run in NHWC; no transpose kernels needed.

#define TILE 16

__device__ __forceinline__ float gelu_exact(float v) {
    // jax.nn.gelu(approximate=False) = 0.5*x*(1+erf(x/sqrt(2)))
    return 0.5f * v * (1.0f + erff(v * 0.70710678118654752f));
}

// Generic NHWC 3x3 SAME conv, optionally grouped.
//  grid.x = 16 spatial tiles (4x4 of 16x16), grid.y = ceil(OCg/OC_BLOCK),
//  grid.z = B*G. Weights OIHW [total_oc][IC_PER_G][3][3].
//  ACT: 0=none, 1=gelu(exact), 2=sigmoid
template<int IC_PER_G, int OC_BLOCK, int ACT>
__global__ __launch_bounds__(256) void conv3x3_nhwc(
    const float* __restrict__ in, const float* __restrict__ wgt,
    const float* __restrict__ bias, float* __restrict__ out,
    int G, int OCg, int in_stride, int out_stride)
{
    const int H = 64, W = 64;
    const int total_oc = out_stride; // == G*OCg for all our calls
    int g = blockIdx.z % G;
    int b = blockIdx.z / G;
    int ty = blockIdx.x >> 2;
    int tx = blockIdx.x & 3;
    int ly = threadIdx.x >> 4;   // 0..15
    int lx = threadIdx.x & 15;   // 0..15
    int oy = ty * TILE + ly;
    int ox = tx * TILE + lx;
    int oc_local0 = blockIdx.y * OC_BLOCK;
    int oc0 = g * OCg + oc_local0;
    int ic_base = g * IC_PER_G;

    // channel-major LDS: smem[ic][18*18], row stride 325 (non-pow2 -> ~conflict-free)
    __shared__ float smem[8 * 325];

    float acc[OC_BLOCK];
#pragma unroll
    for (int j = 0; j < OC_BLOCK; j++) {
        int oc = min(oc0 + j, total_oc - 1);
        acc[j] = bias[oc];
    }

    const float* inb = in + (size_t)b * H * W * in_stride;

    for (int c0 = 0; c0 < IC_PER_G; c0 += 8) {
        __syncthreads();
        // stage 18x18 halo tile x 8 input channels
        for (int pix = threadIdx.x; pix < 324; pix += 256) {
            int py = pix / 18;
            int px = pix - py * 18;
            int gy = ty * TILE + py - 1;
            int gx = tx * TILE + px - 1;
            float4 v0, v1;
            if (gy >= 0 && gy < H && gx >= 0 && gx < W) {
                const float4* p = (const float4*)(inb + ((size_t)gy * W + gx) * in_stride + ic_base + c0);
                v0 = p[0];
                v1 = p[1];
            } else {
                v0 = make_float4(0.f, 0.f, 0.f, 0.f);
                v1 = v0;
            }
#pragma unroll
            for (int ic = 0; ic < 4; ic++) smem[ic * 325 + pix] = (&v0.x)[ic];
#pragma unroll
            for (int ic = 0; ic < 4; ic++) smem[(4 + ic) * 325 + pix] = (&v1.x)[ic];
        }
        __syncthreads();

#pragma unroll
        for (int kh = 0; kh < 3; kh++) {
#pragma unroll
            for (int kw = 0; kw < 3; kw++) {
                int sbase = (ly + kh) * 18 + (lx + kw);
#pragma unroll
                for (int ic = 0; ic < 8; ic++) {
                    float v = smem[ic * 325 + sbase];
#pragma unroll
                    for (int j = 0; j < OC_BLOCK; j++) {
                        int oc = min(oc0 + j, total_oc - 1); // clamp: no OOB weight read on tail block
                        acc[j] += v * wgt[(((size_t)oc * IC_PER_G + (c0 + ic)) * 3 + kh) * 3 + kw];
                    }
                }
            }
        }
    }

    float* ob = out + ((size_t)b * H * W + (size_t)oy * W + ox) * out_stride;
#pragma unroll
    for (int j = 0; j < OC_BLOCK; j++) {
        if (oc_local0 + j < OCg) {
            float v = acc[j];
            if (ACT == 1) v = gelu_exact(v);
            else if (ACT == 2) v = 1.0f / (1.0f + expf(-v));
            ob[oc0 + j] = v;
        }
    }
}

// Deformable bilinear sampling + modulation + mean over P.
// One wave per (b,g,h,w) point; lane = channel-in-group (Cg=64).
// x: [B,HW,256] (NHWC), off: [B,HW,72] (ch = g*18 + d*9 + p, d=0:x,1:y),
// mod: [B,HW,36] (ch = g*9 + p), out: [B,HW,256].
__global__ __launch_bounds__(256) void deform_sample(
    const float* __restrict__ x, const float* __restrict__ off,
    const float* __restrict__ mod, float* __restrict__ out)
{
    const int W = 64;
    int wave = (int)((blockIdx.x * 256u + threadIdx.x) >> 6);
    int lane = (int)(threadIdx.x & 63u);

    int b  = wave >> 14;          // G*HW = 16384 points per batch
    int g  = (wave >> 12) & 3;
    int hw = wave & 4095;
    int hy = hw >> 6;
    int wx = hw & 63;

    // lanes 0..8 load offsets/mod for point p=lane
    float fx = 0.f, fy = 0.f, fm = 0.f;
    int p = lane;
    if (lane < 9) {
        const float* ob = off + ((size_t)(b << 12) + hw) * 72 + g * 18;
        fx = ob[p];
        fy = ob[9 + p];
        fm = mod[((size_t)(b << 12) + hw) * 36 + g * 9 + p];
    }
    // per-lane coords for p = lane (garbage for lane>=9, never consumed)
    float px = fminf(fmaxf((float)wx + (float)(p % 3 - 1) + fx, 0.f), 63.f);
    float py = fminf(fmaxf((float)hy + (float)(p / 3 - 1) + fy, 0.f), 63.f);
    float x0f = floorf(px), y0f = floorf(py);
    float wxf = px - x0f, wyf = py - y0f;
    int x0 = (int)x0f, y0 = (int)y0f;
    int x1 = min(x0 + 1, 63), y1 = min(y0 + 1, 63);

    const float* xb = x + ((size_t)(b << 12)) * 256 + g * 64 + lane;
    float acc = 0.f;
#pragma unroll
    for (int q = 0; q < 9; q++) {
        int   qx0 = __shfl(x0, q);
        int   qx1 = __shfl(x1, q);
        int   qy0 = __shfl(y0, q);
        int   qy1 = __shfl(y1, q);
        float qwx = __shfl(wxf, q);
        float qwy = __shfl(wyf, q);
        float qm  = __shfl(fm, q);
        float v00 = xb[((size_t)(qy0 * W + qx0)) * 256];
        float v01 = xb[((size_t)(qy0 * W + qx1)) * 256];
        float v10 = xb[((size_t)(qy1 * W + qx0)) * 256];
        float v11 = xb[((size_t)(qy1 * W + qx1)) * 256];
        float vv = v00 * (1.f - qwx) * (1.f - qwy)
                 + v01 * qwx * (1.f - qwy)
                 + v10 * (1.f - qwx) * qwy
                 + v11 * qwx * qwy;
        acc += qm * vv;
    }
    out[((size_t)(b << 12) + hw) * 256 + g * 64 + lane] = acc * (1.f / 9.f);
}

extern "C" void kernel_launch(void* const* d_in, const int* in_sizes, int n_in,
                              void* d_out, int out_size, void* d_ws, size_t ws_size,
                              hipStream_t stream)
{
    const float* x      = (const float*)d_in[0];
    const float* off_w1 = (const float*)d_in[1];
    const float* off_b1 = (const float*)d_in[2];
    const float* off_w2 = (const float*)d_in[3];
    const float* off_b2 = (const float*)d_in[4];
    const float* mod_w1 = (const float*)d_in[5];
    const float* mod_b1 = (const float*)d_in[6];
    const float* mod_w2 = (const float*)d_in[7];
    const float* mod_b2 = (const float*)d_in[8];

    const int B = 4, HW = 64 * 64;
    float* h1   = (float*)d_ws;                       // [B,HW,256] offset-branch gelu out
    float* offo = h1 + (size_t)B * HW * 256;          // [B,HW,72]
    float* m1   = offo + (size_t)B * HW * 72;         // [B,HW,64]  mod-branch gelu out
    float* modo = m1 + (size_t)B * HW * 64;           // [B,HW,36]
    // total ws use: ~28.1 MB

    dim3 blk(256);
    // 1) grouped conv C->C (G=4, Cg=64 in/out per group) + GELU
    conv3x3_nhwc<64, 8, 1><<<dim3(16, 8, B * 4), blk, 0, stream>>>(x, off_w1, off_b1, h1, 4, 64, 256, 256);
    // 2) conv 256->72 (offsets)
    conv3x3_nhwc<256, 8, 0><<<dim3(16, 9, B), blk, 0, stream>>>(h1, off_w2, off_b2, offo, 1, 72, 256, 72);
    // 3) conv 256->64 + GELU (mod)
    conv3x3_nhwc<256, 8, 1><<<dim3(16, 8, B), blk, 0, stream>>>(x, mod_w1, mod_b1, m1, 1, 64, 256, 64);
    // 4) conv 64->36 + sigmoid
    conv3x3_nhwc<64, 8, 2><<<dim3(16, 5, B), blk, 0, stream>>>(m1, mod_w2, mod_b2, modo, 1, 36, 64, 36);
    // 5) deformable bilinear sample + modulate + mean
    deform_sample<<<16384, 256, 0, stream>>>(x, offo, modo, (float*)d_out);
}

// Round 2
// 434.273 us; speedup vs baseline: 4.9132x; 4.9132x over previous
//
#include <hip/hip_runtime.h>
#include <math.h>

// B=4, C=256, H=W=64, G=4, Cg=64, P=9. x [B,HW,C] is NHWC already.
// Convs via implicit-GEMM MFMA (bf16 2-term split: hi*hi + hi*lo + lo*hi),
// inputs pre-padded to [66][66][C] split-bf16 in ws -> no border branches.

typedef __attribute__((ext_vector_type(8))) short short8;
typedef __attribute__((ext_vector_type(4))) float floatx4;

__device__ __forceinline__ unsigned short f2bf(float f) {
    unsigned u = __float_as_uint(f);
    u = (u + 0x7FFFu + ((u >> 16) & 1u)) >> 16;
    return (unsigned short)u;
}
__device__ __forceinline__ float bf2f(unsigned short h) {
    return __uint_as_float(((unsigned)h) << 16);
}
__device__ __forceinline__ void split2(float v, unsigned short* hi, unsigned short* lo) {
    unsigned short h = f2bf(v);
    *hi = h;
    *lo = f2bf(v - bf2f(h));
}

// ---------------- MFMA implicit-GEMM conv core ----------------
// Padded NHWC input [b][66][66][astride] split bf16 (hi/lo ushort arrays).
// Weights [tap(9)][OCPAD][IC] split bf16. Wave tile: 32 pixels x OCPAD.
// Block = 4 waves = 128 consecutive pixels (2 image rows). mblock in [0,32).
// A frag: m=lane&15 -> pixel, k=quad*8+j -> ic. B frag: n=lane&15 -> oc.
// C/D: col(oc)=lane&15, row(pixel)=quad*4+reg.
// ACT: 0 none, 1 gelu(exact), 2 sigmoid. OUTMODE: 0 fp32 NHWC, 1 split-pad bf16.
template<int IC, int NT, int ACT, int OUTMODE>
__device__ __forceinline__ void conv_core(
    const unsigned short* __restrict__ ah, const unsigned short* __restrict__ al,
    int astride, int icbase,
    const unsigned short* __restrict__ wh, const unsigned short* __restrict__ wl,
    const float* __restrict__ bias,
    int b, int mblock,
    float* __restrict__ outf, int oc_real,
    unsigned short* __restrict__ oh, unsigned short* __restrict__ ol,
    int ostride, int ocbase)
{
    const int OCPAD = NT * 16;
    int wave = threadIdx.x >> 6;
    int lane = threadIdx.x & 63;
    int quad = lane >> 4;
    int l16 = lane & 15;

    int pix0 = mblock * 128 + wave * 32;   // [0,4096), 32 px in one image row
    int y = pix0 >> 6;
    int x0 = pix0 & 63;

    floatx4 acc[2][NT];
#pragma unroll
    for (int nt = 0; nt < NT; nt++) {
        float bv = bias[nt * 16 + l16];
#pragma unroll
        for (int mt = 0; mt < 2; mt++) { floatx4 v = {bv, bv, bv, bv}; acc[mt][nt] = v; }
    }

    size_t ibase = (size_t)b * 4356 * astride + icbase + quad * 8;

#pragma unroll 1
    for (int tap = 0; tap < 9; tap++) {
        int kh = tap / 3, kw = tap - kh * 3;
        size_t rowoff = ibase + (size_t)((y + kh) * 66 + (x0 + kw) + l16) * astride;
        const unsigned short* pah = ah + rowoff;
        const unsigned short* pal = al + rowoff;
        const unsigned short* pwh = wh + (size_t)(tap * OCPAD + l16) * IC + quad * 8;
        const unsigned short* pwl = wl + (size_t)(tap * OCPAD + l16) * IC + quad * 8;
        for (int c0 = 0; c0 < IC; c0 += 32) {
            short8 a_h[2], a_l[2];
#pragma unroll
            for (int mt = 0; mt < 2; mt++) {
                a_h[mt] = *(const short8*)(pah + (size_t)(mt * 16) * astride + c0);
                a_l[mt] = *(const short8*)(pal + (size_t)(mt * 16) * astride + c0);
            }
#pragma unroll
            for (int nt = 0; nt < NT; nt++) {
                short8 b_h = *(const short8*)(pwh + (size_t)(nt * 16) * IC + c0);
                short8 b_l = *(const short8*)(pwl + (size_t)(nt * 16) * IC + c0);
#pragma unroll
                for (int mt = 0; mt < 2; mt++) {
                    acc[mt][nt] = __builtin_amdgcn_mfma_f32_16x16x32_bf16(a_h[mt], b_h, acc[mt][nt], 0, 0, 0);
                    acc[mt][nt] = __builtin_amdgcn_mfma_f32_16x16x32_bf16(a_h[mt], b_l, acc[mt][nt], 0, 0, 0);
                    acc[mt][nt] = __builtin_amdgcn_mfma_f32_16x16x32_bf16(a_l[mt], b_h, acc[mt][nt], 0, 0, 0);
                }
            }
        }
    }

#pragma unroll
    for (int nt = 0; nt < NT; nt++) {
        int oc = nt * 16 + l16;
#pragma unroll
        for (int mt = 0; mt < 2; mt++) {
#pragma unroll
            for (int r = 0; r < 4; r++) {
                float v = acc[mt][nt][r];
                if (ACT == 1) v = 0.5f * v * (1.0f + erff(v * 0.70710678118654752f));
                else if (ACT == 2) v = 1.0f / (1.0f + expf(-v));
                int px = pix0 + mt * 16 + quad * 4 + r;
                if (OUTMODE == 0) {
                    if (oc < oc_real)
                        outf[((size_t)b * 4096 + px) * oc_real + oc] = v;
                } else {
                    int yy = (px >> 6) + 1, xx = (px & 63) + 1;
                    size_t o = ((size_t)b * 4356 + yy * 66 + xx) * ostride + ocbase + oc;
                    unsigned short hv, lv; split2(v, &hv, &lv);
                    oh[o] = hv; ol[o] = lv;
                }
            }
        }
    }
}

// convA: conv1 (grouped C->C, gelu, ->h1pad) fused with conv3 (256->64, gelu, ->m1pad)
__global__ __launch_bounds__(256) void convA_kernel(
    const unsigned short* __restrict__ xph, const unsigned short* __restrict__ xpl,
    const unsigned short* __restrict__ w1h, const unsigned short* __restrict__ w1l,
    const float* __restrict__ off_b1,
    const unsigned short* __restrict__ w3h, const unsigned short* __restrict__ w3l,
    const float* __restrict__ mod_b1,
    unsigned short* __restrict__ h1h, unsigned short* __restrict__ h1l,
    unsigned short* __restrict__ m1h, unsigned short* __restrict__ m1l)
{
    int b = blockIdx.z;
    if (blockIdx.x < 128) {
        int g = blockIdx.x >> 5;
        int mb = blockIdx.x & 31;
        conv_core<64, 4, 1, 1>(xph, xpl, 256, g * 64,
            w1h + (size_t)g * 9 * 64 * 64, w1l + (size_t)g * 9 * 64 * 64, off_b1 + g * 64,
            b, mb, nullptr, 0, h1h, h1l, 256, g * 64);
    } else {
        int mb = blockIdx.x - 128;
        conv_core<256, 4, 1, 1>(xph, xpl, 256, 0, w3h, w3l, mod_b1,
            b, mb, nullptr, 0, m1h, m1l, 64, 0);
    }
}

// convB: conv2 (256->72, ->offo fp32) fused with conv4 (64->36, sigmoid, ->modo fp32)
__global__ __launch_bounds__(256) void convB_kernel(
    const unsigned short* __restrict__ h1h, const unsigned short* __restrict__ h1l,
    const unsigned short* __restrict__ w2h, const unsigned short* __restrict__ w2l,
    const float* __restrict__ b2p,
    const unsigned short* __restrict__ m1h, const unsigned short* __restrict__ m1l,
    const unsigned short* __restrict__ w4h, const unsigned short* __restrict__ w4l,
    const float* __restrict__ b4p,
    float* __restrict__ offo, float* __restrict__ modo)
{
    int b = blockIdx.z;
    if (blockIdx.x < 32) {
        conv_core<256, 5, 0, 0>(h1h, h1l, 256, 0, w2h, w2l, b2p,
            b, blockIdx.x, offo, 72, nullptr, nullptr, 0, 0);
    } else {
        conv_core<64, 3, 2, 0>(m1h, m1l, 64, 0, w4h, w4l, b4p,
            b, blockIdx.x - 32, modo, 36, nullptr, nullptr, 0, 0);
    }
}

// ---------------- prep kernels ----------------
__global__ void prep_x_kernel(const float* __restrict__ x,
                              unsigned short* __restrict__ xph, unsigned short* __restrict__ xpl)
{
    int bid = blockIdx.x;           // b*4356 + i*66 + j
    int c = threadIdx.x;
    int b = bid / 4356;
    int rem = bid - b * 4356;
    int i = rem / 66, j = rem - i * 66;
    float v = 0.f;
    if (i >= 1 && i <= 64 && j >= 1 && j <= 64)
        v = x[((size_t)b * 4096 + (size_t)(i - 1) * 64 + (j - 1)) * 256 + c];
    size_t o = (size_t)bid * 256 + c;
    unsigned short h, l; split2(v, &h, &l);
    xph[o] = h; xpl[o] = l;
}

// OIHW fp32 [groups*oc_real][ic][3][3] -> [g][tap][ocpad][ic] split bf16 (zero-pad oc)
__global__ void prep_w_kernel(const float* __restrict__ w, int ocpad, int oc_real, int ic,
                              unsigned short* __restrict__ outh, unsigned short* __restrict__ outl,
                              int total)
{
    int idx = blockIdx.x * 256 + threadIdx.x;
    if (idx >= total) return;
    int icx = idx % ic;
    int r1 = idx / ic;
    int ocp = r1 % ocpad;
    int r2 = r1 / ocpad;
    int tap = r2 % 9;
    int g = r2 / 9;
    float v = 0.f;
    if (ocp < oc_real) {
        int oc = g * oc_real + ocp;
        v = w[((size_t)oc * ic + icx) * 9 + tap];
    }
    unsigned short h, l; split2(v, &h, &l);
    outh[idx] = h; outl[idx] = l;
}

__global__ void prep_bias_kernel(const float* __restrict__ b2, const float* __restrict__ b4,
                                 float* __restrict__ b2p, float* __restrict__ b4p)
{
    int t = threadIdx.x;
    if (t < 80) b2p[t] = (t < 72) ? b2[t] : 0.f;
    if (t < 48) b4p[t] = (t < 36) ? b4[t] : 0.f;
}

__global__ void zerofill_kernel(uint4* __restrict__ p, int n)
{
    int i = blockIdx.x * 256 + threadIdx.x;
    if (i < n) p[i] = make_uint4(0u, 0u, 0u, 0u);
}

// ---------------- deformable sampling (unchanged, exact fp32) ----------------
__global__ __launch_bounds__(256) void deform_sample(
    const float* __restrict__ x, const float* __restrict__ off,
    const float* __restrict__ mod, float* __restrict__ out)
{
    const int W = 64;
    int wave = (int)((blockIdx.x * 256u + threadIdx.x) >> 6);
    int lane = (int)(threadIdx.x & 63u);

    int b  = wave >> 14;
    int g  = (wave >> 12) & 3;
    int hw = wave & 4095;
    int hy = hw >> 6;
    int wx = hw & 63;

    float fx = 0.f, fy = 0.f, fm = 0.f;
    int p = lane;
    if (lane < 9) {
        const float* ob = off + ((size_t)(b << 12) + hw) * 72 + g * 18;
        fx = ob[p];
        fy = ob[9 + p];
        fm = mod[((size_t)(b << 12) + hw) * 36 + g * 9 + p];
    }
    float px = fminf(fmaxf((float)wx + (float)(p % 3 - 1) + fx, 0.f), 63.f);
    float py = fminf(fmaxf((float)hy + (float)(p / 3 - 1) + fy, 0.f), 63.f);
    float x0f = floorf(px), y0f = floorf(py);
    float wxf = px - x0f, wyf = py - y0f;
    int x0 = (int)x0f, y0 = (int)y0f;
    int x1 = min(x0 + 1, 63), y1 = min(y0 + 1, 63);

    const float* xb = x + ((size_t)(b << 12)) * 256 + g * 64 + lane;
    float acc = 0.f;
#pragma unroll
    for (int q = 0; q < 9; q++) {
        int   qx0 = __shfl(x0, q);
        int   qx1 = __shfl(x1, q);
        int   qy0 = __shfl(y0, q);
        int   qy1 = __shfl(y1, q);
        float qwx = __shfl(wxf, q);
        float qwy = __shfl(wyf, q);
        float qm  = __shfl(fm, q);
        float v00 = xb[((size_t)(qy0 * W + qx0)) * 256];
        float v01 = xb[((size_t)(qy0 * W + qx1)) * 256];
        float v10 = xb[((size_t)(qy1 * W + qx0)) * 256];
        float v11 = xb[((size_t)(qy1 * W + qx1)) * 256];
        float vv = v00 * (1.f - qwx) * (1.f - qwy)
                 + v01 * qwx * (1.f - qwy)
                 + v10 * (1.f - qwx) * qwy
                 + v11 * qwx * qwy;
        acc += qm * vv;
    }
    out[((size_t)(b << 12) + hw) * 256 + g * 64 + lane] = acc * (1.f / 9.f);
}

extern "C" void kernel_launch(void* const* d_in, const int* in_sizes, int n_in,
                              void* d_out, int out_size, void* d_ws, size_t ws_size,
                              hipStream_t stream)
{
    const float* x      = (const float*)d_in[0];
    const float* off_w1 = (const float*)d_in[1];
    const float* off_b1 = (const float*)d_in[2];
    const float* off_w2 = (const float*)d_in[3];
    const float* off_b2 = (const float*)d_in[4];
    const float* mod_w1 = (const float*)d_in[5];
    const float* mod_b1 = (const float*)d_in[6];
    const float* mod_w2 = (const float*)d_in[7];
    const float* mod_b2 = (const float*)d_in[8];

    // ws layout (ushort units; all counts multiple of 8 -> 16B alignment holds)
    const size_t XP = 4u * 4356u * 256u;   // 4,460,544
    const size_t MP = 4u * 4356u * 64u;    // 1,115,136
    const size_t W1 = 4u * 9u * 64u * 64u; // 147,456
    const size_t W2 = 9u * 80u * 256u;     // 184,320
    const size_t W3 = 9u * 64u * 256u;     // 147,456
    const size_t W4 = 9u * 48u * 64u;      // 27,648

    unsigned short* ws = (unsigned short*)d_ws;
    size_t o = 0;
    unsigned short* xph = ws + o; o += XP;
    unsigned short* xpl = ws + o; o += XP;
    unsigned short* h1h = ws + o; o += XP;
    unsigned short* h1l = ws + o; o += XP;
    unsigned short* m1h = ws + o; o += MP;
    unsigned short* m1l = ws + o; o += MP;
    unsigned short* w1h = ws + o; o += W1;
    unsigned short* w1l = ws + o; o += W1;
    unsigned short* w2h = ws + o; o += W2;
    unsigned short* w2l = ws + o; o += W2;
    unsigned short* w3h = ws + o; o += W3;
    unsigned short* w3l = ws + o; o += W3;
    unsigned short* w4h = ws + o; o += W4;
    unsigned short* w4l = ws + o; o += W4;
    float* fbase = (float*)(ws + o);
    float* b2p  = fbase;
    float* b4p  = fbase + 80;
    float* offo = fbase + 128;
    float* modo = offo + (size_t)4 * 4096 * 72;
    size_t need_bytes = o * 2 + ((size_t)128 + 4u*4096u*72u + 4u*4096u*36u) * 4;
    if (ws_size < need_bytes) return;  // deterministic guard (fails loudly via validation)

    // zero h1pad+m1pad (hi,lo) so halo borders are 0; interiors overwritten by convA
    int zf_n = (int)((2 * XP + 2 * MP) / 8);  // uint4 units
    zerofill_kernel<<<(zf_n + 255) / 256, 256, 0, stream>>>((uint4*)h1h, zf_n);
    prep_x_kernel<<<4 * 4356, 256, 0, stream>>>(x, xph, xpl);
    prep_w_kernel<<<(int)(W1 + 255) / 256, 256, 0, stream>>>(off_w1, 64, 64, 64, w1h, w1l, (int)W1);
    prep_w_kernel<<<(int)(W2 + 255) / 256, 256, 0, stream>>>(off_w2, 80, 72, 256, w2h, w2l, (int)W2);
    prep_w_kernel<<<(int)(W3 + 255) / 256, 256, 0, stream>>>(mod_w1, 64, 64, 256, w3h, w3l, (int)W3);
    prep_w_kernel<<<(int)(W4 + 255) / 256, 256, 0, stream>>>(mod_w2, 48, 36, 64, w4h, w4l, (int)W4);
    prep_bias_kernel<<<1, 128, 0, stream>>>(off_b2, mod_b2, b2p, b4p);

    convA_kernel<<<dim3(160, 1, 4), 256, 0, stream>>>(xph, xpl, w1h, w1l, off_b1,
                                                      w3h, w3l, mod_b1, h1h, h1l, m1h, m1l);
    convB_kernel<<<dim3(64, 1, 4), 256, 0, stream>>>(h1h, h1l, w2h, w2l, b2p,
                                                     m1h, m1l, w4h, w4l, b4p, offo, modo);
    deform_sample<<<16384, 256, 0, stream>>>(x, offo, modo, (float*)d_out);
}